// Round 4
// baseline (63.363 us; speedup 1.0000x reference)
//
#include <hip/hip_runtime.h>
#include <stdint.h>

// out[b, q*16+c, do,ho,wo] = sum_{kd,kh,kw} x[b, q*16+c, do+kd-1, ho+kh-1, wo+kw-1]
//                                           * weight[b, 0, c, (kd*3+kh)*3+kw, do,ho,wo]
// x: (2,64,16,64,64) f32; weight: (2,1,16,27,16,64,64) f32; out: (2,64,16,64,64) f32
//
// Block = (b, c, a, ho_tile): computes douts 4a..4a+3 for 16 ho rows, all 4 q.
// x planes staged once per block (6 planes / 4 douts) into a 4-deep LDS ring
// via global_load_lds; weight is a pure nontemporal stream (27 loads/dout/thread).

#define NQ 4
typedef float f4_t __attribute__((ext_vector_type(4)));

// LDS: guard(64) + ring[4 bufs][q=4][hl=18][64] + guard(64)
#define BUF_FLOATS (4 * 18 * 64)   // 4608
#define LDS_FLOATS (64 + 4 * BUF_FLOATS + 64)

__device__ __forceinline__ void async_copy16(const float* gsrc, float* ldst) {
    __builtin_amdgcn_global_load_lds(
        (const __attribute__((address_space(1))) uint32_t*)gsrc,
        (__attribute__((address_space(3))) uint32_t*)ldst, 16, 0, 0);
}

__global__ __launch_bounds__(256) void lconv_kernel(
    const float* __restrict__ x, const float* __restrict__ wt, float* __restrict__ out,
    const float* __restrict__ zp)
{
    __shared__ float lds_raw[LDS_FLOATS];

    const int tid = threadIdx.x;
    const int tw  = tid & 15;   // group of 4 wo
    const int th  = tid >> 4;   // ho row within tile

    int bid = blockIdx.x;
    const int ho_tile = bid & 3;  bid >>= 2;
    const int a       = bid & 3;  bid >>= 2;
    const int c       = bid & 15; bid >>= 4;
    const int b       = bid;      // 0..1

    const int ho_base = ho_tile * 16;
    const int ho  = ho_base + th;
    const int wo0 = tw * 4;
    const int d0  = a * 4;

    // x base for (b,c): q adds 1048576 floats, d adds 4096 floats
    const float* xbase = x + ((size_t)(b * 64 + c) * 16) * 4096;

    // stage plane d -> ring buf (d+1)&3 ; OOB (d or gh) lanes read the zero page.
    auto stage = [&](int d) {
        const int buf   = (d + 1) & 3;
        const bool dok  = ((unsigned)d < 16u);
        float* dbase    = &lds_raw[64 + buf * BUF_FLOATS];
        #pragma unroll
        for (int it = 0; it < 5; ++it) {
            const int i = it * 256 + tid;           // chunk id; 1152 chunks = 18 waves
            if (i < 1152) {
                const int row = i >> 4;             // 0..71  (q*18 + hl)
                const int seg = i & 15;
                const int q   = row / 18;
                const int hl  = row - q * 18;
                const int gh  = ho_base - 1 + hl;
                const bool ok = dok && ((unsigned)gh < 64u);
                const float* src = ok
                    ? (xbase + (size_t)q * 1048576 + (size_t)d * 4096 + (size_t)gh * 64 + seg * 4)
                    : (zp + seg * 4);
                async_copy16(src, dbase + i * 4);   // linear LDS dest = wave base + lane*16
            }
        }
    };

    // prologue: planes d0-1, d0, d0+1
    stage(d0 - 1);
    stage(d0);
    stage(d0 + 1);
    __syncthreads();

    for (int dd4 = 0; dd4 < 4; ++dd4) {     // NOT unrolled: keep I-cache small
        const int dout = d0 + dd4;
        if (dd4 < 3) stage(dout + 2);       // prefetch next plane into the free buf

        const float* wbase = wt + (((size_t)(b * 16 + c) * 27) * 16 + dout) * 4096
                                + (size_t)ho * 64 + wo0;

        float acc[NQ][4];
        #pragma unroll
        for (int q = 0; q < NQ; ++q)
            #pragma unroll
            for (int j = 0; j < 4; ++j) acc[q][j] = 0.f;

        #pragma unroll
        for (int dd = 0; dd < 3; ++dd) {
            const int buf = (dout + dd) & 3;        // plane dout-1+dd
            const float* bbase = &lds_raw[64 + buf * BUF_FLOATS];
            #pragma unroll
            for (int dh = 0; dh < 3; ++dh) {
                float xv[NQ][6];
                #pragma unroll
                for (int q = 0; q < NQ; ++q) {
                    const float* r = bbase + (q * 18 + th + dh) * 64;
                    const f4_t m = *reinterpret_cast<const f4_t*>(r + wo0);
                    xv[q][0] = (tw > 0)  ? r[wo0 - 1] : 0.f;  // prev-row spill / guard, discarded
                    xv[q][1] = m.x; xv[q][2] = m.y; xv[q][3] = m.z; xv[q][4] = m.w;
                    xv[q][5] = (tw < 15) ? r[wo0 + 4] : 0.f;
                }
                #pragma unroll
                for (int dw = 0; dw < 3; ++dw) {
                    const int k = (dd * 3 + dh) * 3 + dw;
                    const f4_t w4 = __builtin_nontemporal_load(
                        reinterpret_cast<const f4_t*>(wbase + (size_t)k * 65536));
                    #pragma unroll
                    for (int q = 0; q < NQ; ++q) {
                        acc[q][0] = fmaf(xv[q][0 + dw], w4.x, acc[q][0]);
                        acc[q][1] = fmaf(xv[q][1 + dw], w4.y, acc[q][1]);
                        acc[q][2] = fmaf(xv[q][2 + dw], w4.z, acc[q][2]);
                        acc[q][3] = fmaf(xv[q][3 + dw], w4.w, acc[q][3]);
                    }
                }
            }
        }

        #pragma unroll
        for (int q = 0; q < NQ; ++q) {
            float* orow = out + ((size_t)(b * 64 + q * 16 + c) * 16 + dout) * 4096
                              + (size_t)ho * 64 + wo0;
            f4_t rr; rr.x = acc[q][0]; rr.y = acc[q][1]; rr.z = acc[q][2]; rr.w = acc[q][3];
            __builtin_nontemporal_store(rr, reinterpret_cast<f4_t*>(orow));
        }

        __syncthreads();   // drains this iter's stage (vmcnt) + protects ring reuse
    }
}

extern "C" void kernel_launch(void* const* d_in, const int* in_sizes, int n_in,
                              void* d_out, int out_size, void* d_ws, size_t ws_size,
                              hipStream_t stream) {
    const float* x  = (const float*)d_in[0];
    const float* wt = (const float*)d_in[1];
    float* out      = (float*)d_out;

    // 4 KB zero page for OOB staging sources (graph-capture-safe async memset)
    hipMemsetAsync(d_ws, 0, 4096, stream);

    // grid = (b=2) x (c=16) x (a=4 dout-quads) x (ho_tile=4) = 512 blocks
    dim3 grid(512), block(256);
    hipLaunchKernelGGL(lconv_kernel, grid, block, 0, stream, x, wt, out,
                       (const float*)d_ws);
}

// Round 5
// 56.350 us; speedup vs baseline: 1.1244x; 1.1244x over previous
//
#include <hip/hip_runtime.h>
#include <stdint.h>

// out[b, q*16+c, do,ho,wo] = sum_{kd,kh,kw} x[b, q*16+c, do+kd-1, ho+kh-1, wo+kw-1]
//                                           * weight[b, 0, c, (kd*3+kh)*3+kw, do,ho,wo]
// x: (2,64,16,64,64) f32; weight: (2,1,16,27,16,64,64) f32; out: (2,64,16,64,64) f32
//
// r3 structure (1 dout/block, 2-buffer LDS ping-pong, 2048 blocks, 4 blocks/CU)
// + global_load_lds staging + value-masked edges + XCD-aware block decode.

#define NQ 4
typedef float f4_t __attribute__((ext_vector_type(4)));

#define BUF_FLOATS (NQ * 18 * 64)              // 4608 floats / plane-slab
#define LDS_FLOATS (16 + 2 * BUF_FLOATS + 16)  // front/back guards for edge reads

__device__ __forceinline__ void async_copy16(const float* gsrc, float* ldst) {
    __builtin_amdgcn_global_load_lds(
        (const __attribute__((address_space(1))) uint32_t*)gsrc,
        (__attribute__((address_space(3))) uint32_t*)ldst, 16, 0, 0);
}

__global__ __launch_bounds__(256) void lconv_kernel(
    const float* __restrict__ x, const float* __restrict__ wt, float* __restrict__ out,
    const float* __restrict__ zp)
{
    __shared__ __align__(16) float lds_raw[LDS_FLOATS];

    const int tid = threadIdx.x;
    const int tw  = tid & 15;   // group of 4 wo
    const int th  = tid >> 4;   // ho row within tile

    // XCD-aware decode (dispatch round-robins bid over 8 XCDs): each XCD owns
    // 4 (b,c) slices; douts of one (b,c) run temporally adjacent -> the 3x
    // re-read x planes stay in that XCD's L2 (~2MB live < 4MB).
    const int bid  = blockIdx.x;
    const int slot = bid >> 3;
    const int bc   = (bid & 7) * 4 + (slot >> 6);   // 0..31
    const int dout = (slot >> 2) & 15;
    const int ho_tile = slot & 3;
    const int b = bc >> 4, c = bc & 15;

    const int ho_base = ho_tile * 16;
    const int ho  = ho_base + th;
    const int wo0 = tw * 4;

    // x base for (b,c): q adds 1048576 floats, d adds 4096 floats
    const float* xbase = x + ((size_t)(b * 64 + c) * 16) * 4096;

    // stage plane d into buf: 1152 16B chunks, linear LDS dest (wave base+lane*16)
    auto stage = [&](int buf, int d) {
        float* dbase = &lds_raw[16 + buf * BUF_FLOATS];
        #pragma unroll
        for (int it = 0; it < 5; ++it) {
            const int i = it * 256 + tid;          // chunk id
            if (it < 4 || i < 1152) {
                const int row = i >> 4;            // q*18 + hl
                const int seg = i & 15;
                const int q   = row / 18;
                const int hl  = row - q * 18;
                const int gh  = ho_base - 1 + hl;
                const float* src = ((unsigned)gh < 64u)
                    ? (xbase + (size_t)q * 1048576 + (size_t)d * 4096
                             + (size_t)gh * 64 + seg * 4)
                    : (zp + seg * 4);              // zero page for H-pad rows
                async_copy16(src, dbase + (size_t)i * 4);
            }
        }
    };

    float acc[NQ][4];
    #pragma unroll
    for (int q = 0; q < NQ; ++q)
        #pragma unroll
        for (int j = 0; j < 4; ++j) acc[q][j] = 0.f;

    // weight base at k=0
    const float* wbase = wt + (((size_t)(b * 16 + c) * 27) * 16 + dout) * 4096
                            + (size_t)ho * 64 + wo0;

    if (dout > 0) stage(0, dout - 1);
    __syncthreads();

    #pragma unroll
    for (int dd = 0; dd < 3; ++dd) {
        const int cur = dd & 1, nxt = cur ^ 1;
        if (dd < 2 && dout + dd < 16) stage(nxt, dout + dd);  // prefetch next plane

        const int d = dout + dd - 1;
        if ((unsigned)d < 16u) {                  // block-uniform
            const float* bbase = &lds_raw[16 + cur * BUF_FLOATS];
            #pragma unroll
            for (int dh = 0; dh < 3; ++dh) {
                float xv[NQ][6];
                #pragma unroll
                for (int q = 0; q < NQ; ++q) {
                    const float* r = bbase + (q * 18 + th + dh) * 64;
                    const f4_t m = *reinterpret_cast<const f4_t*>(r + wo0);
                    const float xl = r[wo0 - 1];   // constant offsets -> ds_read2
                    const float xr = r[wo0 + 4];
                    xv[q][0] = (tw > 0)  ? xl : 0.f;   // W-pad by value mask
                    xv[q][1] = m.x; xv[q][2] = m.y; xv[q][3] = m.z; xv[q][4] = m.w;
                    xv[q][5] = (tw < 15) ? xr : 0.f;
                }
                #pragma unroll
                for (int dw = 0; dw < 3; ++dw) {
                    const int k = (dd * 3 + dh) * 3 + dw;
                    const f4_t w4 = __builtin_nontemporal_load(
                        reinterpret_cast<const f4_t*>(wbase + (size_t)k * 65536));
                    #pragma unroll
                    for (int q = 0; q < NQ; ++q) {
                        acc[q][0] = fmaf(xv[q][0 + dw], w4.x, acc[q][0]);
                        acc[q][1] = fmaf(xv[q][1 + dw], w4.y, acc[q][1]);
                        acc[q][2] = fmaf(xv[q][2 + dw], w4.z, acc[q][2]);
                        acc[q][3] = fmaf(xv[q][3 + dw], w4.w, acc[q][3]);
                    }
                }
            }
        }
        if (dd < 2) __syncthreads();   // drains stage vmcnt + protects ping-pong
    }

    #pragma unroll
    for (int q = 0; q < NQ; ++q) {
        float* orow = out + ((size_t)(b * 64 + q * 16 + c) * 16 + dout) * 4096
                          + (size_t)ho * 64 + wo0;
        f4_t rr; rr.x = acc[q][0]; rr.y = acc[q][1]; rr.z = acc[q][2]; rr.w = acc[q][3];
        __builtin_nontemporal_store(rr, reinterpret_cast<f4_t*>(orow));
    }
}

extern "C" void kernel_launch(void* const* d_in, const int* in_sizes, int n_in,
                              void* d_out, int out_size, void* d_ws, size_t ws_size,
                              hipStream_t stream) {
    const float* x  = (const float*)d_in[0];
    const float* wt = (const float*)d_in[1];
    float* out      = (float*)d_out;

    // zero page for H-pad staging sources (graph-capture-safe async memset)
    hipMemsetAsync(d_ws, 0, 4096, stream);

    // 2048 blocks = 8 XCD x 4 bc x 16 dout x 4 ho_tile
    dim3 grid(2048), block(256);
    hipLaunchKernelGGL(lconv_kernel, grid, block, 0, stream, x, wt, out,
                       (const float*)d_ws);
}